// Round 9
// baseline (733.171 us; speedup 1.0000x reference)
//
#include <hip/hip_runtime.h>
#include <hip/hip_bf16.h>
#include <hip/hip_cooperative_groups.h>

namespace cg = cooperative_groups;

#define NU 100000
#define NI 100000
#define NEDGE 600000
#define DIN 128
#define DOUT 16
#define NPAD 100032   // 1563 * 64; also 6252 * 16
#define BSH 9         // coarse bucket shift
#define NBUCK 196     // ceil(100000 / 512)
#define NSB 256       // coarse-sort blocks per etype
#define SCH 2344      // edges per coarse-sort block (256*2344 >= 600000)
#define SORTGRID 768  // 3 * NSB

typedef __attribute__((ext_vector_type(8))) short short8;
typedef __attribute__((ext_vector_type(4))) float f32x4;

// ---- workspace word offsets ----
#define W_EU   0ull          // 6,400,000 w bf16 user table (live until fused kernel done)
#define W_AUI  6400000ull    // packed pairs (sort scratch, u32/edge) live here pre-agg
#define W_AUU  12802048ull   // M/Btot/Bbase alias head pre-sort; P_iu/P_uu after sort
#define W_AIU  19204096ull   // (unused now)
#define W_PW   25606144ull   // packed weights, 26,624 w
#define W_OFFU 25632768ull   // 100,016 w each
#define W_OFFI 25732784ull
#define W_OFFX 25832800ull
#define W_SUU  25932816ull   // 600,000 w each
#define W_SIU  26532816ull
#define W_SUI  27132816ull
#define W_EI   27732944ull   // 6,400,000 w (optional)
#define WS_FULL_BYTES (34132944ull * 4)

__device__ inline unsigned pack_bf16(float x, float y) {
  __hip_bfloat162 h = __float22bfloat162_rn(make_float2(x, y));
  unsigned u;
  __builtin_memcpy(&u, &h, 4);
  return u;
}

__device__ inline short bf16_bits(float x) {
  __hip_bfloat16 h = __float2bfloat16(x);
  short s;
  __builtin_memcpy(&s, &h, 2);
  return s;
}

__device__ inline void bf2_accw(unsigned u, float w, float& ax, float& ay) {
  unsigned lo = u << 16, hi = u & 0xffff0000u;
  float f0, f1;
  __builtin_memcpy(&f0, &lo, 4);
  __builtin_memcpy(&f1, &hi, 4);
  ax = fmaf(f0, w, ax);
  ay = fmaf(f1, w, ay);
}

// ============== cooperative: conversion + repack + full sort chain in ONE kernel ==============
// Replaces prep/scanM/scanB/coarse_scatter/fine_sort (5 launches -> 1). 768 blocks x 256.
// Phase 0 units are independent (conversion | hist | weight repack) -> grid-stride, no sync.
// grid.sync() between dependent phases. Pairs packed to u32: (localdst<<17)|src (src<2^17).
__global__ __launch_bounds__(256) void sortprep_kernel(
    const float* __restrict__ Eu, const float* __restrict__ Ei,
    unsigned* __restrict__ Eu_b, unsigned* __restrict__ Ei_b,
    const int* __restrict__ d_uu, const int* __restrict__ d_iu, const int* __restrict__ d_ui,
    const int* __restrict__ s_uu, const int* __restrict__ s_iu, const int* __restrict__ s_ui,
    int* __restrict__ M, int* __restrict__ Btot, int* __restrict__ Bbase,
    unsigned* __restrict__ pairs,
    int* __restrict__ off_uu, int* __restrict__ off_iu, int* __restrict__ off_ui,
    int* __restrict__ ssrc_uu, int* __restrict__ ssrc_iu, int* __restrict__ ssrc_ui,
    const float* __restrict__ W0_uu, const float* __restrict__ W0_ui,
    const float* __restrict__ W0_iu, const float* __restrict__ W1_uu,
    const float* __restrict__ W1_iu,
    short* __restrict__ pW0_uu, short* __restrict__ pW0_ui, short* __restrict__ pW0_iu,
    short* __restrict__ pW1_uu, short* __restrict__ pW1_iu,
    int nconvU, int nconvI) {
  cg::grid_group grid = cg::this_grid();
  __shared__ int sh[520];  // fine: h[512] + wls[4]; hist: [196]; scans: wls/tot
  const int tid = threadIdx.x;
  const int bid = blockIdx.x;
  const int lane = tid & 63, wv = tid >> 6;

  // ---------------- phase 0: conversion + hist + weight repack (independent) ----------------
  {
    const int UC = nconvU + nconvI;
    const int UH = 3 * NSB;
    const int UT = UC + UH + 208;
    for (int u = bid; u < UT; u += SORTGRID) {
      if (u < UC) {
        const float* src;
        unsigned* dst;
        int t;
        if (u < nconvU) { src = Eu; dst = Eu_b; t = u * 256 + tid; }
        else { src = Ei; dst = Ei_b; t = (u - nconvU) * 256 + tid; }
        const float4* s4 = (const float4*)src;
        float4 x = s4[(size_t)t * 2], y = s4[(size_t)t * 2 + 1];
        uint4 o;
        o.x = pack_bf16(x.x, x.y);
        o.y = pack_bf16(x.z, x.w);
        o.z = pack_bf16(y.x, y.y);
        o.w = pack_bf16(y.z, y.w);
        ((uint4*)dst)[t] = o;
      } else if (u < UC + UH) {
        int b = u - UC;
        int t = b / NSB, k = b % NSB;
        if (tid < NBUCK) sh[tid] = 0;
        __syncthreads();
        const int* d = (t == 0) ? d_uu : (t == 1) ? d_iu : d_ui;
        int e0 = k * SCH, e1 = min(e0 + SCH, NEDGE);
        for (int e = e0 + tid; e < e1; e += 256) atomicAdd(&sh[d[e] >> BSH], 1);
        __syncthreads();
        if (tid < NBUCK) M[t * (NBUCK * NSB) + tid * NSB + k] = sh[tid];
        __syncthreads();  // protect sh before next grid-stride iteration
      } else {
        int t = (u - UC - UH) * 256 + tid;
        const float* src;
        short* dst;
        int base;
        bool w1 = false;
        bool ok = true;
        if (t < 16384) { src = W0_uu; dst = pW0_uu; base = t; }
        else if (t < 32768) { src = W0_ui; dst = pW0_ui; base = t - 16384; }
        else if (t < 49152) { src = W0_iu; dst = pW0_iu; base = t - 32768; }
        else if (t < 51200) { src = W1_uu; dst = pW1_uu; base = t - 49152; w1 = true; }
        else if (t < 53248) { src = W1_iu; dst = pW1_iu; base = t - 51200; w1 = true; }
        else ok = false;
        if (ok) {
          int j = base & 7;
          int ln = (base >> 3) & 63;
          int frag = base >> 9;
          int quad = ln >> 4, l16 = ln & 15;
          float val;
          if (!w1) {
            int kc = frag >> 3, nt = frag & 7;
            val = src[(kc * 32 + quad * 8 + j) * 128 + nt * 16 + l16];
          } else {
            int kc = frag;
            val = src[(kc * 32 + quad * 8 + j) * 16 + l16];
          }
          dst[base] = bf16_bits(val);
        }
      }
    }
  }
  grid.sync();

  // ---------------- phase 1: scanM (588 blocks active) ----------------
  if (bid < 3 * NBUCK) {
    int t = bid / NBUCK, b = bid % NBUCK;
    int* Mt = M + t * (NBUCK * NSB) + b * NSB;
    int* wls = sh + 512;
    int v = Mt[tid];
    int x = v;
#pragma unroll
    for (int d = 1; d < 64; d <<= 1) {
      int y = __shfl_up(x, d, 64);
      if (lane >= d) x += y;
    }
    if (lane == 63) wls[wv] = x;
    __syncthreads();
    if (tid == 0) {
      int r = 0;
#pragma unroll
      for (int i = 0; i < 4; i++) { int tt = wls[i]; wls[i] = r; r += tt; }
      sh[516] = r;
    }
    __syncthreads();
    Mt[tid] = x - v + wls[wv];  // local exclusive offset within bucket
    if (tid == 0) Btot[t * NBUCK + b] = sh[516];
  }
  grid.sync();

  // ---------------- phase 2: scanB (3 blocks active) ----------------
  if (bid < 3) {
    int t = bid;
    int* wls = sh + 512;
    int v = (tid < NBUCK) ? Btot[t * NBUCK + tid] : 0;
    int x = v;
#pragma unroll
    for (int d = 1; d < 64; d <<= 1) {
      int y = __shfl_up(x, d, 64);
      if (lane >= d) x += y;
    }
    if (lane == 63) wls[wv] = x;
    __syncthreads();
    if (tid == 0) {
      int r = 0;
#pragma unroll
      for (int i = 0; i < 4; i++) { int tt = wls[i]; wls[i] = r; r += tt; }
    }
    __syncthreads();
    if (tid < NBUCK) Bbase[t * NBUCK + tid] = x - v + wls[wv];
  }
  grid.sync();

  // ---------------- phase 3: coarse scatter (all 768 blocks), packed u32 pairs ----------------
  {
    int t = bid / NSB, k = bid % NSB;
    if (tid < NBUCK) sh[tid] = M[t * (NBUCK * NSB) + tid * NSB + k] + Bbase[t * NBUCK + tid];
    __syncthreads();
    const int* src = (t == 0) ? s_uu : (t == 1) ? s_iu : s_ui;
    const int* dst = (t == 0) ? d_uu : (t == 1) ? d_iu : d_ui;
    unsigned* pr = pairs + (size_t)t * NEDGE;
    int e0 = k * SCH, e1 = min(e0 + SCH, NEDGE);
    for (int e = e0 + tid; e < e1; e += 256) {
      int d = dst[e];
      int pos = atomicAdd(&sh[d >> BSH], 1);
      pr[pos] = ((unsigned)(d & ((1 << BSH) - 1)) << 17) | (unsigned)src[e];
    }
  }
  grid.sync();

  // ---------------- phase 4: fine sort (588 blocks active), packed u32 pairs ----------------
  if (bid < 3 * NBUCK) {
    int t = bid / NBUCK, b = bid % NBUCK;
    int* h = sh;
    int* wls = sh + 512;
    int* off = (t == 0) ? off_uu : (t == 1) ? off_iu : off_ui;
    int* ss = (t == 0) ? ssrc_uu : (t == 1) ? ssrc_iu : ssrc_ui;
    const unsigned* pr = pairs + (size_t)t * NEDGE;
    int base = b << BSH;
    int base_off = Bbase[t * NBUCK + b];
    int cnt = Btot[t * NBUCK + b];
    h[tid] = 0;
    h[tid + 256] = 0;
    __syncthreads();
    for (int e = base_off + tid; e < base_off + cnt; e += 256)
      atomicAdd(&h[pr[e] >> 17], 1);
    __syncthreads();
    int h0 = h[2 * tid], h1 = h[2 * tid + 1];
    int s = h0 + h1, x = s;
#pragma unroll
    for (int d = 1; d < 64; d <<= 1) {
      int y = __shfl_up(x, d, 64);
      if (lane >= d) x += y;
    }
    if (lane == 63) wls[wv] = x;
    __syncthreads();
    if (tid == 0) {
      int r = 0;
#pragma unroll
      for (int i = 0; i < 4; i++) { int tt = wls[i]; wls[i] = r; r += tt; }
    }
    __syncthreads();
    int excl = base_off + x - s + wls[wv];
    h[2 * tid] = excl;
    h[2 * tid + 1] = excl + h0;
    __syncthreads();
    int nn = min(1 << BSH, NU - base);
    for (int i = tid; i < nn; i += 256) off[base + i] = h[i];
    if (b == NBUCK - 1 && tid == 0) off[NU] = base_off + cnt;  // = NEDGE
    __syncthreads();
    for (int e = base_off + tid; e < base_off + cnt; e += 256) {
      unsigned p = pr[e];
      int pos = atomicAdd(&h[p >> 17], 1);
      ss[pos] = (int)(p & 0x1FFFFu);
    }
  }
}

// ---------------- fused: gather+mean into LDS -> MFMA L0(+relu) -> MFMA L1 -> P ----------------
// ONE WAVE PER BLOCK (64 threads), 16 dst rows per block. R8's measured-best body (fp32 h
// stride 20, VGPR 64, 106us): dual-row gather ILP, LJF ordering, kc=0 weight prefetch.
__global__ __launch_bounds__(64, 4) void fused_layer_kernel(
    const uint4* __restrict__ Xu4, const void* __restrict__ Xi, int xi_bf16,
    const int* __restrict__ off_ui, const int* __restrict__ off_uu, const int* __restrict__ off_iu,
    const int* __restrict__ s_ui, const int* __restrict__ s_uu, const int* __restrict__ s_iu,
    const short* __restrict__ pW0_ui, const short* __restrict__ pW0_uu,
    const short* __restrict__ pW0_iu, const float* __restrict__ b0_ui,
    const float* __restrict__ b0_uu, const float* __restrict__ b0_iu,
    const short* __restrict__ pW1_iu, const short* __restrict__ pW1_uu,
    const float* __restrict__ b1_iu, const float* __restrict__ b1_uu,
    float* __restrict__ P_iu, float* __restrict__ P_uu, int nbi) {
  __shared__ __align__(16) float hs[2560];

  const int lane = threadIdx.x;  // one wave
  const bool user = (int)blockIdx.x < nbi;   // LJF: user (long) blocks first
  const int blk = user ? (int)blockIdx.x : (int)blockIdx.x - nbi;
  const int rb = blk * 16;  // global row base of this wave's 16 rows

  float* hw = &hs[0];
  uint4* A0 = (uint4*)hw;        // 16 rows x 16 chunks(16B) = 4KB
  uint4* A1 = A0 + 256;          // next 4KB

  // ---- gather phase: 4 groups x 16 feature-lanes; group g does rows g*4..g*4+3,
  //      two rows in flight at a time (16 outstanding dwordx4 gathers) ----
  {
    const int g = lane >> 4, l16 = lane & 15;
    const int npass = user ? 2 : 1;
#pragma unroll 1
    for (int pass = 0; pass < npass; pass++) {
      const int* off = pass ? off_iu : (user ? off_uu : off_ui);
      const int* ss = pass ? s_iu : (user ? s_uu : s_ui);
      uint4* A = pass ? A1 : A0;
      const bool bf = pass ? (xi_bf16 != 0) : true;
      const uint4* X = pass ? (const uint4*)Xi : Xu4;
      const float4* Xf = (const float4*)Xi;
      if (bf) {
#pragma unroll 1
        for (int ip = 0; ip < 2; ip++) {
          int rA = g * 4 + ip * 2, rB = rA + 1;
          int nodeA = rb + rA, nodeB = rb + rB;
          float acA[8], acB[8];
#pragma unroll
          for (int j = 0; j < 8; j++) { acA[j] = 0.f; acB[j] = 0.f; }
          int s0A = 0, s1A = 0, s0B = 0, s1B = 0;
          if (nodeA < NU) { s0A = off[nodeA]; s1A = off[nodeA + 1]; }
          if (nodeB < NU) { s0B = off[nodeB]; s1B = off[nodeB + 1]; }
          int degA = s1A - s0A, degB = s1B - s0B;
#pragma unroll 1
          for (int eA = s0A, eB = s0B; eA < s1A || eB < s1B; eA += 8, eB += 8) {
            int idxA[8], idxB[8];
            float wtA[8], wtB[8];
#pragma unroll
            for (int j = 0; j < 8; j++) {
              int ea = eA + j, eb = eB + j;
              wtA[j] = (ea < s1A) ? 1.f : 0.f;
              wtB[j] = (eb < s1B) ? 1.f : 0.f;
              idxA[j] = ss[max(min(ea, s1A - 1), 0)];
              idxB[j] = ss[max(min(eb, s1B - 1), 0)];
            }
            uint4 vA[8], vB[8];
#pragma unroll
            for (int j = 0; j < 8; j++) vA[j] = X[(size_t)idxA[j] * 16 + l16];
#pragma unroll
            for (int j = 0; j < 8; j++) vB[j] = X[(size_t)idxB[j] * 16 + l16];
#pragma unroll
            for (int j = 0; j < 8; j++) {
              bf2_accw(vA[j].x, wtA[j], acA[0], acA[1]);
              bf2_accw(vA[j].y, wtA[j], acA[2], acA[3]);
              bf2_accw(vA[j].z, wtA[j], acA[4], acA[5]);
              bf2_accw(vA[j].w, wtA[j], acA[6], acA[7]);
            }
#pragma unroll
            for (int j = 0; j < 8; j++) {
              bf2_accw(vB[j].x, wtB[j], acB[0], acB[1]);
              bf2_accw(vB[j].y, wtB[j], acB[2], acB[3]);
              bf2_accw(vB[j].z, wtB[j], acB[4], acB[5]);
              bf2_accw(vB[j].w, wtB[j], acB[6], acB[7]);
            }
          }
          float invA = 1.0f / fmaxf((float)degA, 1.0f);
          float invB = 1.0f / fmaxf((float)degB, 1.0f);
          uint4 oA, oB;
          oA.x = pack_bf16(acA[0] * invA, acA[1] * invA);
          oA.y = pack_bf16(acA[2] * invA, acA[3] * invA);
          oA.z = pack_bf16(acA[4] * invA, acA[5] * invA);
          oA.w = pack_bf16(acA[6] * invA, acA[7] * invA);
          oB.x = pack_bf16(acB[0] * invB, acB[1] * invB);
          oB.y = pack_bf16(acB[2] * invB, acB[3] * invB);
          oB.z = pack_bf16(acB[4] * invB, acB[5] * invB);
          oB.w = pack_bf16(acB[6] * invB, acB[7] * invB);
          A[rA * 16 + (l16 ^ (rA & 7))] = oA;  // swizzled chunk store
          A[rB * 16 + (l16 ^ (rB & 7))] = oB;
        }
      } else {
        // fp32 fallback path (workspace-limited mode), per-row as before
#pragma unroll 1
        for (int it = 0; it < 4; it++) {
          int r = g * 4 + it;
          int node = rb + r;
          float ac[8];
#pragma unroll
          for (int j = 0; j < 8; j++) ac[j] = 0.f;
          int deg = 0;
          if (node < NU) {
            int s0 = off[node], s1 = off[node + 1];
            deg = s1 - s0;
            if (deg > 0) {
              for (int e = s0; e < s1; e += 4) {
                int idx[4];
                float wt[4];
#pragma unroll
                for (int j = 0; j < 4; j++) {
                  int ee = e + j;
                  bool v = ee < s1;
                  idx[j] = ss[v ? ee : s1 - 1];
                  wt[j] = v ? 1.f : 0.f;
                }
#pragma unroll
                for (int j = 0; j < 4; j++) {
                  float4 pa = Xf[(size_t)idx[j] * 32 + l16 * 2];
                  float4 qa = Xf[(size_t)idx[j] * 32 + l16 * 2 + 1];
                  ac[0] = fmaf(pa.x, wt[j], ac[0]); ac[1] = fmaf(pa.y, wt[j], ac[1]);
                  ac[2] = fmaf(pa.z, wt[j], ac[2]); ac[3] = fmaf(pa.w, wt[j], ac[3]);
                  ac[4] = fmaf(qa.x, wt[j], ac[4]); ac[5] = fmaf(qa.y, wt[j], ac[5]);
                  ac[6] = fmaf(qa.z, wt[j], ac[6]); ac[7] = fmaf(qa.w, wt[j], ac[7]);
                }
              }
            }
          }
          float inv = 1.0f / fmaxf((float)deg, 1.0f);
          uint4 o;
          o.x = pack_bf16(ac[0] * inv, ac[1] * inv);
          o.y = pack_bf16(ac[2] * inv, ac[3] * inv);
          o.z = pack_bf16(ac[4] * inv, ac[5] * inv);
          o.w = pack_bf16(ac[6] * inv, ac[7] * inv);
          A[r * 16 + (l16 ^ (r & 7))] = o;
        }
      }
    }
  }

  // ---- kc=0 weight prefetch (issued before barrier; hides L2 latency under gather drain) ----
  const short8* B0p = (const short8*)(user ? pW0_uu : pW0_ui);
  short8 b0pre[8];
#pragma unroll
  for (int nt = 0; nt < 8; nt++) b0pre[nt] = B0p[nt * 64 + lane];

  __syncthreads();  // single-wave barrier: orders LDS writes vs reads

  // ---- layer-0 MFMA (A from LDS) ----
  const int quad = lane >> 4, q16 = lane & 15;
  const int* off0 = user ? off_uu : off_ui;
  const float* b0a = user ? b0_uu : b0_ui;
  const short* W1p = user ? pW1_uu : pW1_iu;
  const float* b1v = user ? b1_uu : b1_iu;
  float* P = user ? P_uu : P_iu;

  float m0[4], m1[4];
#pragma unroll
  for (int r = 0; r < 4; r++) {
    int rr = rb + quad * 4 + r;
    m0[r] = 0.f;
    m1[r] = 0.f;
    if (rr < NU) {
      m0[r] = (off0[rr + 1] > off0[rr]) ? 1.f : 0.f;
      if (user) m1[r] = (off_iu[rr + 1] > off_iu[rr]) ? 1.f : 0.f;
    }
  }

  f32x4 acc[8];
#pragma unroll
  for (int nt = 0; nt < 8; nt++) {
    float ba = b0a[nt * 16 + q16];
    float bb = user ? b0_iu[nt * 16 + q16] : 0.f;
#pragma unroll
    for (int r = 0; r < 4; r++) acc[nt][r] = ba * m0[r] + bb * m1[r];
  }

  const short8* B1p = (const short8*)pW0_iu;
  union u4s8 { uint4 u; short8 s; };
#pragma unroll
  for (int kc = 0; kc < 4; kc++) {
    int c = kc * 4 + quad;
    u4s8 a0, a1;
    a0.u = A0[q16 * 16 + (c ^ (q16 & 7))];
    if (user) a1.u = A1[q16 * 16 + (c ^ (q16 & 7))];
#pragma unroll
    for (int nt = 0; nt < 8; nt++) {
      short8 b0 = (kc == 0) ? b0pre[nt] : B0p[(kc * 8 + nt) * 64 + lane];
      acc[nt] = __builtin_amdgcn_mfma_f32_16x16x32_bf16(a0.s, b0, acc[nt], 0, 0, 0);
      if (user) {
        short8 bb = B1p[(kc * 8 + nt) * 64 + lane];
        acc[nt] = __builtin_amdgcn_mfma_f32_16x16x32_bf16(a1.s, bb, acc[nt], 0, 0, 0);
      }
    }
  }
  __syncthreads();  // A tiles dead -> reuse region for h

  // ---- relu + h to LDS (col-major, stride 20) ----
#pragma unroll
  for (int nt = 0; nt < 8; nt++) {
    int col = nt * 16 + q16;
    float4 v;
    v.x = fmaxf(acc[nt][0], 0.f);
    v.y = fmaxf(acc[nt][1], 0.f);
    v.z = fmaxf(acc[nt][2], 0.f);
    v.w = fmaxf(acc[nt][3], 0.f);
    *(float4*)&hw[col * 20 + quad * 4] = v;
  }
  __syncthreads();

  // ---- layer-1 MFMA ----
  f32x4 acc2;
  {
    float bv = b1v[q16];
    acc2[0] = bv; acc2[1] = bv; acc2[2] = bv; acc2[3] = bv;
  }
  const short8* W1f = (const short8*)W1p;
#pragma unroll
  for (int kc = 0; kc < 4; kc++) {
    float f[8];
#pragma unroll
    for (int j = 0; j < 8; j++) f[j] = hw[(kc * 32 + quad * 8 + j) * 20 + q16];
    union { uint4 u; short8 s; } hf;
    hf.u.x = pack_bf16(f[0], f[1]);
    hf.u.y = pack_bf16(f[2], f[3]);
    hf.u.z = pack_bf16(f[4], f[5]);
    hf.u.w = pack_bf16(f[6], f[7]);
    short8 bw = W1f[kc * 64 + lane];
    acc2 = __builtin_amdgcn_mfma_f32_16x16x32_bf16(hf.s, bw, acc2, 0, 0, 0);
  }
#pragma unroll
  for (int r = 0; r < 4; r++) {
    int rr = rb + quad * 4 + r;
    if (rr < NU) P[(size_t)rr * DOUT + q16] = acc2[r];
  }
}

// ---------------- fused output: 4 nodes/wave x 4 edge-slots x float4, 4 edges in flight ----
__global__ __launch_bounds__(256) void out_kernel(const float4* __restrict__ P_uu,
                                                  const float4* __restrict__ P_iu,
                                                  const int* __restrict__ off_uu,
                                                  const int* __restrict__ s_uu,
                                                  const int* __restrict__ off_iu,
                                                  const int* __restrict__ s_iu,
                                                  float4* __restrict__ out) {
  int w = threadIdx.x >> 6, lane = threadIdx.x & 63;
  int q = lane & 3;            // float4 quad within 16-float row
  int sl = (lane >> 2) & 3;    // edge slot
  int nl = lane >> 4;          // node within wave
  int node = blockIdx.x * 16 + w * 4 + nl;  // NU == 6250*16 exactly
  float4 a = make_float4(0.f, 0.f, 0.f, 0.f);
  float4 b = a;
  int s0 = off_uu[node], s1 = off_uu[node + 1];
  for (int e = s0 + sl; e < s1; e += 16) {
    // 4 edges in flight per slot: clamp index, weight 0/1
    int idx[4];
    float wt[4];
#pragma unroll
    for (int j = 0; j < 4; j++) {
      int ee = e + j * 4;
      bool v = ee < s1;
      idx[j] = s_uu[v ? ee : s1 - 1];
      wt[j] = v ? 1.f : 0.f;
    }
    float4 vv[4];
#pragma unroll
    for (int j = 0; j < 4; j++) vv[j] = P_uu[(size_t)idx[j] * 4 + q];
#pragma unroll
    for (int j = 0; j < 4; j++) {
      a.x = fmaf(vv[j].x, wt[j], a.x); a.y = fmaf(vv[j].y, wt[j], a.y);
      a.z = fmaf(vv[j].z, wt[j], a.z); a.w = fmaf(vv[j].w, wt[j], a.w);
    }
  }
  int t0 = off_iu[node], t1 = off_iu[node + 1];
  for (int e = t0 + sl; e < t1; e += 16) {
    int idx[4];
    float wt[4];
#pragma unroll
    for (int j = 0; j < 4; j++) {
      int ee = e + j * 4;
      bool v = ee < t1;
      idx[j] = s_iu[v ? ee : t1 - 1];
      wt[j] = v ? 1.f : 0.f;
    }
    float4 vv[4];
#pragma unroll
    for (int j = 0; j < 4; j++) vv[j] = P_iu[(size_t)idx[j] * 4 + q];
#pragma unroll
    for (int j = 0; j < 4; j++) {
      b.x = fmaf(vv[j].x, wt[j], b.x); b.y = fmaf(vv[j].y, wt[j], b.y);
      b.z = fmaf(vv[j].z, wt[j], b.z); b.w = fmaf(vv[j].w, wt[j], b.w);
    }
  }
  float ia = 1.0f / fmaxf((float)(s1 - s0), 1.0f);
  float ib = 1.0f / fmaxf((float)(t1 - t0), 1.0f);
  float4 r;
  r.x = a.x * ia + b.x * ib;
  r.y = a.y * ia + b.y * ib;
  r.z = a.z * ia + b.z * ib;
  r.w = a.w * ia + b.w * ib;
  // reduce across the 4 edge slots (lane bits 2-3)
  r.x += __shfl_xor(r.x, 4, 64); r.y += __shfl_xor(r.y, 4, 64);
  r.z += __shfl_xor(r.z, 4, 64); r.w += __shfl_xor(r.w, 4, 64);
  r.x += __shfl_xor(r.x, 8, 64); r.y += __shfl_xor(r.y, 8, 64);
  r.z += __shfl_xor(r.z, 8, 64); r.w += __shfl_xor(r.w, 8, 64);
  if (sl == 0) out[(size_t)node * 4 + q] = r;
}

extern "C" void kernel_launch(void* const* d_in, const int* in_sizes, int n_in,
                              void* d_out, int out_size, void* d_ws, size_t ws_size,
                              hipStream_t stream) {
  (void)in_sizes; (void)n_in; (void)out_size;
  const float* embed_user = (const float*)d_in[0];
  const float* embed_item = (const float*)d_in[1];
  const int* src_uu = (const int*)d_in[2];
  const int* dst_uu = (const int*)d_in[3];
  const int* src_ui = (const int*)d_in[4];
  const int* dst_ui = (const int*)d_in[5];
  const int* src_iu = (const int*)d_in[6];
  const int* dst_iu = (const int*)d_in[7];
  const float* W0_uu = (const float*)d_in[8];
  const float* b0_uu = (const float*)d_in[9];
  const float* W0_ui = (const float*)d_in[10];
  const float* b0_ui = (const float*)d_in[11];
  const float* W0_iu = (const float*)d_in[12];
  const float* b0_iu = (const float*)d_in[13];
  const float* W1_uu = (const float*)d_in[14];
  const float* b1_uu = (const float*)d_in[15];
  const float* W1_iu = (const float*)d_in[18];
  const float* b1_iu = (const float*)d_in[19];
  float* out = (float*)d_out;

  char* ws = (char*)d_ws;
  unsigned* Eu_b = (unsigned*)(ws + W_EU * 4);
  short* pW0_uu = (short*)(ws + W_PW * 4);
  short* pW0_ui = pW0_uu + 16384;
  short* pW0_iu = pW0_uu + 32768;
  short* pW1_uu = pW0_uu + 49152;
  short* pW1_iu = pW0_uu + 51200;
  int* off_uu = (int*)(ws + W_OFFU * 4);
  int* off_iu = (int*)(ws + W_OFFI * 4);
  int* off_ui = (int*)(ws + W_OFFX * 4);
  int* ssrc_uu = (int*)(ws + W_SUU * 4);
  int* ssrc_iu = (int*)(ws + W_SIU * 4);
  int* ssrc_ui = (int*)(ws + W_SUI * 4);
  unsigned* Ei_b = (unsigned*)(ws + W_EI * 4);
  unsigned* pairs = (unsigned*)(ws + W_AUI * 4);  // packed u32/edge, dead after sort
  int* M = (int*)(ws + W_AUU * 4);                // 150,528 w, dead after sort
  int* Btot = M + NBUCK * NSB * 3;                // 588 w
  int* Bbase = Btot + NBUCK * 3;                  // 588 w
  // P tables reuse the (dead after sort) M / A_uu region; Eu_b stays live through the
  // fused kernel (it is gathered there), so P may NOT alias Eu_b.
  float* P_iu = (float*)(ws + W_AUU * 4);
  float* P_uu = P_iu + 1600000;

  const int full = (ws_size >= WS_FULL_BYTES) ? 1 : 0;
  int nconvU = 6250, nconvI = full ? 6250 : 0;
  const void* Xi = full ? (const void*)Ei_b : (const void*)embed_item;

  // ---- ONE cooperative kernel for conversion + repack + whole sort chain ----
  {
    void* args[] = {
        (void*)&embed_user, (void*)&embed_item, (void*)&Eu_b, (void*)&Ei_b,
        (void*)&dst_uu, (void*)&dst_iu, (void*)&dst_ui,
        (void*)&src_uu, (void*)&src_iu, (void*)&src_ui,
        (void*)&M, (void*)&Btot, (void*)&Bbase, (void*)&pairs,
        (void*)&off_uu, (void*)&off_iu, (void*)&off_ui,
        (void*)&ssrc_uu, (void*)&ssrc_iu, (void*)&ssrc_ui,
        (void*)&W0_uu, (void*)&W0_ui, (void*)&W0_iu, (void*)&W1_uu, (void*)&W1_iu,
        (void*)&pW0_uu, (void*)&pW0_ui, (void*)&pW0_iu, (void*)&pW1_uu, (void*)&pW1_iu,
        (void*)&nconvU, (void*)&nconvI};
    hipLaunchCooperativeKernel((const void*)sortprep_kernel, dim3(SORTGRID), dim3(256),
                               args, 0, stream);
  }

  const int nbi = NPAD / 16;  // 6252 single-wave blocks per class; user blocks first (LJF)
  fused_layer_kernel<<<2 * nbi, 64, 0, stream>>>(
      (const uint4*)Eu_b, Xi, full, off_ui, off_uu, off_iu,
      ssrc_ui, ssrc_uu, ssrc_iu,
      pW0_ui, pW0_uu, pW0_iu, b0_ui, b0_uu, b0_iu,
      pW1_iu, pW1_uu, b1_iu, b1_uu, P_iu, P_uu, nbi);

  out_kernel<<<NU / 16, 256, 0, stream>>>((const float4*)P_uu, (const float4*)P_iu,
                                          off_uu, ssrc_uu, off_iu, ssrc_iu,
                                          (float4*)out);
}

// Round 10
// 339.243 us; speedup vs baseline: 2.1612x; 2.1612x over previous
//
#include <hip/hip_runtime.h>
#include <hip/hip_bf16.h>

#define NU 100000
#define NI 100000
#define NEDGE 600000
#define DIN 128
#define DOUT 16
#define NPAD 100032   // 1563 * 64; also 6252 * 16
#define BSH 9         // coarse bucket shift
#define NBUCK 196     // ceil(100000 / 512)
#define NSB 256       // scatter blocks per etype
#define SCH 2344      // edges per scatter block (256*2344 >= 600000)
#define BSTRIDE 4096  // fixed pairs-slot per bucket (max bucket ~3250, 18-sigma margin)

typedef __attribute__((ext_vector_type(8))) short short8;
typedef __attribute__((ext_vector_type(4))) float f32x4;

// ---- workspace word offsets ----
#define W_EU   0ull          // 6,400,000 w bf16 user table (live until fused kernel done)
#define W_AUI  6400000ull    // packed pairs: 3 * 196 * 4096 = 2,408,448 u32 (sort scratch)
#define W_AUU  12802048ull   // bcnt (588 w) aliases head pre-fused; P_iu/P_uu after sort
#define W_AIU  19204096ull   // (unused now)
#define W_PW   25606144ull   // packed weights, 26,624 w
#define W_OFFU 25632768ull   // 100,016 w each
#define W_OFFI 25732784ull
#define W_OFFX 25832800ull
#define W_SUU  25932816ull   // 600,000 w each
#define W_SIU  26532816ull
#define W_SUI  27132816ull
#define W_EI   27732944ull   // 6,400,000 w (optional)
#define WS_FULL_BYTES (34132944ull * 4)

__device__ inline unsigned pack_bf16(float x, float y) {
  __hip_bfloat162 h = __float22bfloat162_rn(make_float2(x, y));
  unsigned u;
  __builtin_memcpy(&u, &h, 4);
  return u;
}

__device__ inline short bf16_bits(float x) {
  __hip_bfloat16 h = __float2bfloat16(x);
  short s;
  __builtin_memcpy(&s, &h, 2);
  return s;
}

__device__ inline void bf2_accw(unsigned u, float w, float& ax, float& ay) {
  unsigned lo = u << 16, hi = u & 0xffff0000u;
  float f0, f1;
  __builtin_memcpy(&f0, &lo, 4);
  __builtin_memcpy(&f1, &hi, 4);
  ax = fmaf(f0, w, ax);
  ay = fmaf(f1, w, ay);
}

// ---------------- prep: embed->bf16 + weight repack + zero bucket counters ----------------
// (hist pass removed: the atomic-reserve scatter does its own LDS hist)
__global__ __launch_bounds__(256) void prep_kernel(
    const float* __restrict__ Eu, const float* __restrict__ Ei,
    unsigned* __restrict__ Eu_b, unsigned* __restrict__ Ei_b,
    int* __restrict__ bcnt,
    const float* __restrict__ W0_uu, const float* __restrict__ W0_ui,
    const float* __restrict__ W0_iu, const float* __restrict__ W1_uu,
    const float* __restrict__ W1_iu, short* __restrict__ pW0_uu, short* __restrict__ pW0_ui,
    short* __restrict__ pW0_iu, short* __restrict__ pW1_uu, short* __restrict__ pW1_iu,
    int nconvU, int nconvI) {
  int b = blockIdx.x;
  int tid = threadIdx.x;
  if (b < nconvU + nconvI) {
    const float* src;
    unsigned* dst;
    int t;
    if (b < nconvU) { src = Eu; dst = Eu_b; t = b * 256 + tid; }
    else { src = Ei; dst = Ei_b; t = (b - nconvU) * 256 + tid; }
    const float4* s4 = (const float4*)src;
    float4 x = s4[(size_t)t * 2], y = s4[(size_t)t * 2 + 1];
    uint4 o;
    o.x = pack_bf16(x.x, x.y);
    o.y = pack_bf16(x.z, x.w);
    o.z = pack_bf16(y.x, y.y);
    o.w = pack_bf16(y.z, y.w);
    ((uint4*)dst)[t] = o;
    return;
  }
  b -= nconvU + nconvI;
  if (b == 208) {  // zero the 3*NBUCK bucket counters
    for (int i = tid; i < 3 * NBUCK; i += 256) bcnt[i] = 0;
    return;
  }
  int t = b * 256 + tid;
  const float* src;
  short* dst;
  int base;
  bool w1 = false;
  if (t < 16384) { src = W0_uu; dst = pW0_uu; base = t; }
  else if (t < 32768) { src = W0_ui; dst = pW0_ui; base = t - 16384; }
  else if (t < 49152) { src = W0_iu; dst = pW0_iu; base = t - 32768; }
  else if (t < 51200) { src = W1_uu; dst = pW1_uu; base = t - 49152; w1 = true; }
  else if (t < 53248) { src = W1_iu; dst = pW1_iu; base = t - 51200; w1 = true; }
  else return;
  int j = base & 7;
  int lane = (base >> 3) & 63;
  int frag = base >> 9;
  int quad = lane >> 4, l16 = lane & 15;
  float val;
  if (!w1) {
    int kc = frag >> 3, nt = frag & 7;
    val = src[(kc * 32 + quad * 8 + j) * 128 + nt * 16 + l16];
  } else {
    int kc = frag;
    val = src[(kc * 32 + quad * 8 + j) * 16 + l16];
  }
  dst[base] = bf16_bits(val);
}

// -------- scatter: LDS hist -> atomic reserve per bucket -> packed u32 pair writes --------
// Replaces hist/scanM/scanB/coarse_scatter. Bucket b of etype t owns pairs slot
// [t*NBUCK*BSTRIDE + b*BSTRIDE, +BSTRIDE). Within-bucket block order is nondeterministic
// (atomic reserve), which only permutes fp32 summation order downstream.
__global__ __launch_bounds__(256) void scatter_kernel(
    const int* __restrict__ s_uu, const int* __restrict__ d_uu,
    const int* __restrict__ s_iu, const int* __restrict__ d_iu,
    const int* __restrict__ s_ui, const int* __restrict__ d_ui,
    int* __restrict__ bcnt, unsigned* __restrict__ pairs) {
  __shared__ int h[NBUCK];
  __shared__ int cur[NBUCK];
  int t = blockIdx.x / NSB, k = blockIdx.x % NSB;
  int tid = threadIdx.x;
  const int* src = (t == 0) ? s_uu : (t == 1) ? s_iu : s_ui;
  const int* dst = (t == 0) ? d_uu : (t == 1) ? d_iu : d_ui;
  if (tid < NBUCK) h[tid] = 0;
  __syncthreads();
  int e0 = k * SCH, e1 = min(e0 + SCH, NEDGE);
  for (int e = e0 + tid; e < e1; e += 256) atomicAdd(&h[dst[e] >> BSH], 1);
  __syncthreads();
  if (tid < NBUCK) {
    int c = h[tid];
    int r = (c > 0) ? atomicAdd(&bcnt[t * NBUCK + tid], c) : 0;
    cur[tid] = t * (NBUCK * BSTRIDE) + tid * BSTRIDE + r;
  }
  __syncthreads();
  for (int e = e0 + tid; e < e1; e += 256) {
    int d = dst[e];
    int pos = atomicAdd(&cur[d >> BSH], 1);
    pairs[pos] = ((unsigned)(d & ((1 << BSH) - 1)) << 17) | (unsigned)src[e];
  }
}

// -------- fine sort: redundant bucket-prefix + LDS hist/scan -> off[] + ssrc scatter --------
__global__ __launch_bounds__(256) void fine_sort_kernel(
    const unsigned* __restrict__ pairs, const int* __restrict__ bcnt,
    int* __restrict__ off_uu, int* __restrict__ off_iu, int* __restrict__ off_ui,
    int* __restrict__ ssrc_uu, int* __restrict__ ssrc_iu, int* __restrict__ ssrc_ui) {
  __shared__ int h[1 << BSH];
  __shared__ int wls[4];
  __shared__ int pfx[256];  // exclusive prefix of bucket counts (per etype)
  int t = blockIdx.x / NBUCK, b = blockIdx.x % NBUCK;
  int tid = threadIdx.x, lane = tid & 63, wv = tid >> 6;
  int* off = (t == 0) ? off_uu : (t == 1) ? off_iu : off_ui;
  int* ss = (t == 0) ? ssrc_uu : (t == 1) ? ssrc_iu : ssrc_ui;
  // ---- redundant per-block exclusive prefix over this etype's 196 bucket counts ----
  {
    int v = (tid < NBUCK) ? bcnt[t * NBUCK + tid] : 0;
    int x = v;
#pragma unroll
    for (int d = 1; d < 64; d <<= 1) {
      int y = __shfl_up(x, d, 64);
      if (lane >= d) x += y;
    }
    if (lane == 63) wls[wv] = x;
    __syncthreads();
    if (tid == 0) {
      int r = 0;
#pragma unroll
      for (int i = 0; i < 4; i++) { int tt = wls[i]; wls[i] = r; r += tt; }
    }
    __syncthreads();
    pfx[tid] = x - v + wls[wv];
    __syncthreads();
  }
  int base = b << BSH;
  int base_off = pfx[b];                  // this bucket's edge base in dense order
  int cnt = bcnt[t * NBUCK + b];
  const unsigned* pr = pairs + (size_t)t * (NBUCK * BSTRIDE) + (size_t)b * BSTRIDE;
  h[tid] = 0;
  h[tid + 256] = 0;
  __syncthreads();
  for (int e = tid; e < cnt; e += 256) atomicAdd(&h[pr[e] >> 17], 1);
  __syncthreads();
  int h0 = h[2 * tid], h1 = h[2 * tid + 1];
  int s = h0 + h1, x = s;
#pragma unroll
  for (int d = 1; d < 64; d <<= 1) {
    int y = __shfl_up(x, d, 64);
    if (lane >= d) x += y;
  }
  if (lane == 63) wls[wv] = x;
  __syncthreads();
  if (tid == 0) {
    int r = 0;
#pragma unroll
    for (int i = 0; i < 4; i++) { int tt = wls[i]; wls[i] = r; r += tt; }
  }
  __syncthreads();
  int excl = base_off + x - s + wls[wv];
  h[2 * tid] = excl;
  h[2 * tid + 1] = excl + h0;
  __syncthreads();
  int nn = min(1 << BSH, NU - base);
  for (int i = tid; i < nn; i += 256) off[base + i] = h[i];
  if (b == NBUCK - 1 && tid == 0) off[NU] = base_off + cnt;  // = NEDGE
  __syncthreads();
  for (int e = tid; e < cnt; e += 256) {
    unsigned p = pr[e];
    int pos = atomicAdd(&h[p >> 17], 1);
    ss[pos] = (int)(p & 0x1FFFFu);
  }
}

// ---------------- fused: gather+mean into LDS -> MFMA L0(+relu) -> MFMA L1 -> P ----------------
// ONE WAVE PER BLOCK (64 threads), 16 dst rows per block. R8's measured-best body (fp32 h
// stride 20, VGPR 64, 106us): dual-row gather ILP, LJF ordering, kc=0 weight prefetch.
__global__ __launch_bounds__(64, 4) void fused_layer_kernel(
    const uint4* __restrict__ Xu4, const void* __restrict__ Xi, int xi_bf16,
    const int* __restrict__ off_ui, const int* __restrict__ off_uu, const int* __restrict__ off_iu,
    const int* __restrict__ s_ui, const int* __restrict__ s_uu, const int* __restrict__ s_iu,
    const short* __restrict__ pW0_ui, const short* __restrict__ pW0_uu,
    const short* __restrict__ pW0_iu, const float* __restrict__ b0_ui,
    const float* __restrict__ b0_uu, const float* __restrict__ b0_iu,
    const short* __restrict__ pW1_iu, const short* __restrict__ pW1_uu,
    const float* __restrict__ b1_iu, const float* __restrict__ b1_uu,
    float* __restrict__ P_iu, float* __restrict__ P_uu, int nbi) {
  __shared__ __align__(16) float hs[2560];

  const int lane = threadIdx.x;  // one wave
  const bool user = (int)blockIdx.x < nbi;   // LJF: user (long) blocks first
  const int blk = user ? (int)blockIdx.x : (int)blockIdx.x - nbi;
  const int rb = blk * 16;  // global row base of this wave's 16 rows

  float* hw = &hs[0];
  uint4* A0 = (uint4*)hw;        // 16 rows x 16 chunks(16B) = 4KB
  uint4* A1 = A0 + 256;          // next 4KB

  // ---- gather phase: 4 groups x 16 feature-lanes; group g does rows g*4..g*4+3,
  //      two rows in flight at a time (16 outstanding dwordx4 gathers) ----
  {
    const int g = lane >> 4, l16 = lane & 15;
    const int npass = user ? 2 : 1;
#pragma unroll 1
    for (int pass = 0; pass < npass; pass++) {
      const int* off = pass ? off_iu : (user ? off_uu : off_ui);
      const int* ss = pass ? s_iu : (user ? s_uu : s_ui);
      uint4* A = pass ? A1 : A0;
      const bool bf = pass ? (xi_bf16 != 0) : true;
      const uint4* X = pass ? (const uint4*)Xi : Xu4;
      const float4* Xf = (const float4*)Xi;
      if (bf) {
#pragma unroll 1
        for (int ip = 0; ip < 2; ip++) {
          int rA = g * 4 + ip * 2, rB = rA + 1;
          int nodeA = rb + rA, nodeB = rb + rB;
          float acA[8], acB[8];
#pragma unroll
          for (int j = 0; j < 8; j++) { acA[j] = 0.f; acB[j] = 0.f; }
          int s0A = 0, s1A = 0, s0B = 0, s1B = 0;
          if (nodeA < NU) { s0A = off[nodeA]; s1A = off[nodeA + 1]; }
          if (nodeB < NU) { s0B = off[nodeB]; s1B = off[nodeB + 1]; }
          int degA = s1A - s0A, degB = s1B - s0B;
#pragma unroll 1
          for (int eA = s0A, eB = s0B; eA < s1A || eB < s1B; eA += 8, eB += 8) {
            int idxA[8], idxB[8];
            float wtA[8], wtB[8];
#pragma unroll
            for (int j = 0; j < 8; j++) {
              int ea = eA + j, eb = eB + j;
              wtA[j] = (ea < s1A) ? 1.f : 0.f;
              wtB[j] = (eb < s1B) ? 1.f : 0.f;
              idxA[j] = ss[max(min(ea, s1A - 1), 0)];
              idxB[j] = ss[max(min(eb, s1B - 1), 0)];
            }
            uint4 vA[8], vB[8];
#pragma unroll
            for (int j = 0; j < 8; j++) vA[j] = X[(size_t)idxA[j] * 16 + l16];
#pragma unroll
            for (int j = 0; j < 8; j++) vB[j] = X[(size_t)idxB[j] * 16 + l16];
#pragma unroll
            for (int j = 0; j < 8; j++) {
              bf2_accw(vA[j].x, wtA[j], acA[0], acA[1]);
              bf2_accw(vA[j].y, wtA[j], acA[2], acA[3]);
              bf2_accw(vA[j].z, wtA[j], acA[4], acA[5]);
              bf2_accw(vA[j].w, wtA[j], acA[6], acA[7]);
            }
#pragma unroll
            for (int j = 0; j < 8; j++) {
              bf2_accw(vB[j].x, wtB[j], acB[0], acB[1]);
              bf2_accw(vB[j].y, wtB[j], acB[2], acB[3]);
              bf2_accw(vB[j].z, wtB[j], acB[4], acB[5]);
              bf2_accw(vB[j].w, wtB[j], acB[6], acB[7]);
            }
          }
          float invA = 1.0f / fmaxf((float)degA, 1.0f);
          float invB = 1.0f / fmaxf((float)degB, 1.0f);
          uint4 oA, oB;
          oA.x = pack_bf16(acA[0] * invA, acA[1] * invA);
          oA.y = pack_bf16(acA[2] * invA, acA[3] * invA);
          oA.z = pack_bf16(acA[4] * invA, acA[5] * invA);
          oA.w = pack_bf16(acA[6] * invA, acA[7] * invA);
          oB.x = pack_bf16(acB[0] * invB, acB[1] * invB);
          oB.y = pack_bf16(acB[2] * invB, acB[3] * invB);
          oB.z = pack_bf16(acB[4] * invB, acB[5] * invB);
          oB.w = pack_bf16(acB[6] * invB, acB[7] * invB);
          A[rA * 16 + (l16 ^ (rA & 7))] = oA;  // swizzled chunk store
          A[rB * 16 + (l16 ^ (rB & 7))] = oB;
        }
      } else {
        // fp32 fallback path (workspace-limited mode), per-row as before
#pragma unroll 1
        for (int it = 0; it < 4; it++) {
          int r = g * 4 + it;
          int node = rb + r;
          float ac[8];
#pragma unroll
          for (int j = 0; j < 8; j++) ac[j] = 0.f;
          int deg = 0;
          if (node < NU) {
            int s0 = off[node], s1 = off[node + 1];
            deg = s1 - s0;
            if (deg > 0) {
              for (int e = s0; e < s1; e += 4) {
                int idx[4];
                float wt[4];
#pragma unroll
                for (int j = 0; j < 4; j++) {
                  int ee = e + j;
                  bool v = ee < s1;
                  idx[j] = ss[v ? ee : s1 - 1];
                  wt[j] = v ? 1.f : 0.f;
                }
#pragma unroll
                for (int j = 0; j < 4; j++) {
                  float4 pa = Xf[(size_t)idx[j] * 32 + l16 * 2];
                  float4 qa = Xf[(size_t)idx[j] * 32 + l16 * 2 + 1];
                  ac[0] = fmaf(pa.x, wt[j], ac[0]); ac[1] = fmaf(pa.y, wt[j], ac[1]);
                  ac[2] = fmaf(pa.z, wt[j], ac[2]); ac[3] = fmaf(pa.w, wt[j], ac[3]);
                  ac[4] = fmaf(qa.x, wt[j], ac[4]); ac[5] = fmaf(qa.y, wt[j], ac[5]);
                  ac[6] = fmaf(qa.z, wt[j], ac[6]); ac[7] = fmaf(qa.w, wt[j], ac[7]);
                }
              }
            }
          }
          float inv = 1.0f / fmaxf((float)deg, 1.0f);
          uint4 o;
          o.x = pack_bf16(ac[0] * inv, ac[1] * inv);
          o.y = pack_bf16(ac[2] * inv, ac[3] * inv);
          o.z = pack_bf16(ac[4] * inv, ac[5] * inv);
          o.w = pack_bf16(ac[6] * inv, ac[7] * inv);
          A[r * 16 + (l16 ^ (r & 7))] = o;
        }
      }
    }
  }

  // ---- kc=0 weight prefetch (issued before barrier; hides L2 latency under gather drain) ----
  const short8* B0p = (const short8*)(user ? pW0_uu : pW0_ui);
  short8 b0pre[8];
#pragma unroll
  for (int nt = 0; nt < 8; nt++) b0pre[nt] = B0p[nt * 64 + lane];

  __syncthreads();  // single-wave barrier: orders LDS writes vs reads

  // ---- layer-0 MFMA (A from LDS) ----
  const int quad = lane >> 4, q16 = lane & 15;
  const int* off0 = user ? off_uu : off_ui;
  const float* b0a = user ? b0_uu : b0_ui;
  const short* W1p = user ? pW1_uu : pW1_iu;
  const float* b1v = user ? b1_uu : b1_iu;
  float* P = user ? P_uu : P_iu;

  float m0[4], m1[4];
#pragma unroll
  for (int r = 0; r < 4; r++) {
    int rr = rb + quad * 4 + r;
    m0[r] = 0.f;
    m1[r] = 0.f;
    if (rr < NU) {
      m0[r] = (off0[rr + 1] > off0[rr]) ? 1.f : 0.f;
      if (user) m1[r] = (off_iu[rr + 1] > off_iu[rr]) ? 1.f : 0.f;
    }
  }

  f32x4 acc[8];
#pragma unroll
  for (int nt = 0; nt < 8; nt++) {
    float ba = b0a[nt * 16 + q16];
    float bb = user ? b0_iu[nt * 16 + q16] : 0.f;
#pragma unroll
    for (int r = 0; r < 4; r++) acc[nt][r] = ba * m0[r] + bb * m1[r];
  }

  const short8* B1p = (const short8*)pW0_iu;
  union u4s8 { uint4 u; short8 s; };
#pragma unroll
  for (int kc = 0; kc < 4; kc++) {
    int c = kc * 4 + quad;
    u4s8 a0, a1;
    a0.u = A0[q16 * 16 + (c ^ (q16 & 7))];
    if (user) a1.u = A1[q16 * 16 + (c ^ (q16 & 7))];
#pragma unroll
    for (int nt = 0; nt < 8; nt++) {
      short8 b0 = (kc == 0) ? b0pre[nt] : B0p[(kc * 8 + nt) * 64 + lane];
      acc[nt] = __builtin_amdgcn_mfma_f32_16x16x32_bf16(a0.s, b0, acc[nt], 0, 0, 0);
      if (user) {
        short8 bb = B1p[(kc * 8 + nt) * 64 + lane];
        acc[nt] = __builtin_amdgcn_mfma_f32_16x16x32_bf16(a1.s, bb, acc[nt], 0, 0, 0);
      }
    }
  }
  __syncthreads();  // A tiles dead -> reuse region for h

  // ---- relu + h to LDS (col-major, stride 20) ----
#pragma unroll
  for (int nt = 0; nt < 8; nt++) {
    int col = nt * 16 + q16;
    float4 v;
    v.x = fmaxf(acc[nt][0], 0.f);
    v.y = fmaxf(acc[nt][1], 0.f);
    v.z = fmaxf(acc[nt][2], 0.f);
    v.w = fmaxf(acc[nt][3], 0.f);
    *(float4*)&hw[col * 20 + quad * 4] = v;
  }
  __syncthreads();

  // ---- layer-1 MFMA ----
  f32x4 acc2;
  {
    float bv = b1v[q16];
    acc2[0] = bv; acc2[1] = bv; acc2[2] = bv; acc2[3] = bv;
  }
  const short8* W1f = (const short8*)W1p;
#pragma unroll
  for (int kc = 0; kc < 4; kc++) {
    float f[8];
#pragma unroll
    for (int j = 0; j < 8; j++) f[j] = hw[(kc * 32 + quad * 8 + j) * 20 + q16];
    union { uint4 u; short8 s; } hf;
    hf.u.x = pack_bf16(f[0], f[1]);
    hf.u.y = pack_bf16(f[2], f[3]);
    hf.u.z = pack_bf16(f[4], f[5]);
    hf.u.w = pack_bf16(f[6], f[7]);
    short8 bw = W1f[kc * 64 + lane];
    acc2 = __builtin_amdgcn_mfma_f32_16x16x32_bf16(hf.s, bw, acc2, 0, 0, 0);
  }
#pragma unroll
  for (int r = 0; r < 4; r++) {
    int rr = rb + quad * 4 + r;
    if (rr < NU) P[(size_t)rr * DOUT + q16] = acc2[r];
  }
}

// ---------------- fused output: 4 nodes/wave x 4 edge-slots x float4, 4 edges in flight ----
__global__ __launch_bounds__(256) void out_kernel(const float4* __restrict__ P_uu,
                                                  const float4* __restrict__ P_iu,
                                                  const int* __restrict__ off_uu,
                                                  const int* __restrict__ s_uu,
                                                  const int* __restrict__ off_iu,
                                                  const int* __restrict__ s_iu,
                                                  float4* __restrict__ out) {
  int w = threadIdx.x >> 6, lane = threadIdx.x & 63;
  int q = lane & 3;            // float4 quad within 16-float row
  int sl = (lane >> 2) & 3;    // edge slot
  int nl = lane >> 4;          // node within wave
  int node = blockIdx.x * 16 + w * 4 + nl;  // NU == 6250*16 exactly
  float4 a = make_float4(0.f, 0.f, 0.f, 0.f);
  float4 b = a;
  int s0 = off_uu[node], s1 = off_uu[node + 1];
  for (int e = s0 + sl; e < s1; e += 16) {
    // 4 edges in flight per slot: clamp index, weight 0/1
    int idx[4];
    float wt[4];
#pragma unroll
    for (int j = 0; j < 4; j++) {
      int ee = e + j * 4;
      bool v = ee < s1;
      idx[j] = s_uu[v ? ee : s1 - 1];
      wt[j] = v ? 1.f : 0.f;
    }
    float4 vv[4];
#pragma unroll
    for (int j = 0; j < 4; j++) vv[j] = P_uu[(size_t)idx[j] * 4 + q];
#pragma unroll
    for (int j = 0; j < 4; j++) {
      a.x = fmaf(vv[j].x, wt[j], a.x); a.y = fmaf(vv[j].y, wt[j], a.y);
      a.z = fmaf(vv[j].z, wt[j], a.z); a.w = fmaf(vv[j].w, wt[j], a.w);
    }
  }
  int t0 = off_iu[node], t1 = off_iu[node + 1];
  for (int e = t0 + sl; e < t1; e += 16) {
    int idx[4];
    float wt[4];
#pragma unroll
    for (int j = 0; j < 4; j++) {
      int ee = e + j * 4;
      bool v = ee < t1;
      idx[j] = s_iu[v ? ee : t1 - 1];
      wt[j] = v ? 1.f : 0.f;
    }
    float4 vv[4];
#pragma unroll
    for (int j = 0; j < 4; j++) vv[j] = P_iu[(size_t)idx[j] * 4 + q];
#pragma unroll
    for (int j = 0; j < 4; j++) {
      b.x = fmaf(vv[j].x, wt[j], b.x); b.y = fmaf(vv[j].y, wt[j], b.y);
      b.z = fmaf(vv[j].z, wt[j], b.z); b.w = fmaf(vv[j].w, wt[j], b.w);
    }
  }
  float ia = 1.0f / fmaxf((float)(s1 - s0), 1.0f);
  float ib = 1.0f / fmaxf((float)(t1 - t0), 1.0f);
  float4 r;
  r.x = a.x * ia + b.x * ib;
  r.y = a.y * ia + b.y * ib;
  r.z = a.z * ia + b.z * ib;
  r.w = a.w * ia + b.w * ib;
  // reduce across the 4 edge slots (lane bits 2-3)
  r.x += __shfl_xor(r.x, 4, 64); r.y += __shfl_xor(r.y, 4, 64);
  r.z += __shfl_xor(r.z, 4, 64); r.w += __shfl_xor(r.w, 4, 64);
  r.x += __shfl_xor(r.x, 8, 64); r.y += __shfl_xor(r.y, 8, 64);
  r.z += __shfl_xor(r.z, 8, 64); r.w += __shfl_xor(r.w, 8, 64);
  if (sl == 0) out[(size_t)node * 4 + q] = r;
}

extern "C" void kernel_launch(void* const* d_in, const int* in_sizes, int n_in,
                              void* d_out, int out_size, void* d_ws, size_t ws_size,
                              hipStream_t stream) {
  (void)in_sizes; (void)n_in; (void)out_size;
  const float* embed_user = (const float*)d_in[0];
  const float* embed_item = (const float*)d_in[1];
  const int* src_uu = (const int*)d_in[2];
  const int* dst_uu = (const int*)d_in[3];
  const int* src_ui = (const int*)d_in[4];
  const int* dst_ui = (const int*)d_in[5];
  const int* src_iu = (const int*)d_in[6];
  const int* dst_iu = (const int*)d_in[7];
  const float* W0_uu = (const float*)d_in[8];
  const float* b0_uu = (const float*)d_in[9];
  const float* W0_ui = (const float*)d_in[10];
  const float* b0_ui = (const float*)d_in[11];
  const float* W0_iu = (const float*)d_in[12];
  const float* b0_iu = (const float*)d_in[13];
  const float* W1_uu = (const float*)d_in[14];
  const float* b1_uu = (const float*)d_in[15];
  const float* W1_iu = (const float*)d_in[18];
  const float* b1_iu = (const float*)d_in[19];
  float* out = (float*)d_out;

  char* ws = (char*)d_ws;
  unsigned* Eu_b = (unsigned*)(ws + W_EU * 4);
  short* pW0_uu = (short*)(ws + W_PW * 4);
  short* pW0_ui = pW0_uu + 16384;
  short* pW0_iu = pW0_uu + 32768;
  short* pW1_uu = pW0_uu + 49152;
  short* pW1_iu = pW0_uu + 51200;
  int* off_uu = (int*)(ws + W_OFFU * 4);
  int* off_iu = (int*)(ws + W_OFFI * 4);
  int* off_ui = (int*)(ws + W_OFFX * 4);
  int* ssrc_uu = (int*)(ws + W_SUU * 4);
  int* ssrc_iu = (int*)(ws + W_SIU * 4);
  int* ssrc_ui = (int*)(ws + W_SUI * 4);
  unsigned* Ei_b = (unsigned*)(ws + W_EI * 4);
  unsigned* pairs = (unsigned*)(ws + W_AUI * 4);  // 2,408,448 u32, dead after fine_sort
  int* bcnt = (int*)(ws + W_AUU * 4);             // 588 w, dead after fine_sort
  // P tables reuse the (dead after fine_sort) bcnt / A_uu region; Eu_b stays live through
  // the fused kernel (it is gathered there), so P may NOT alias Eu_b.
  float* P_iu = (float*)(ws + W_AUU * 4);
  float* P_uu = P_iu + 1600000;

  const int full = (ws_size >= WS_FULL_BYTES) ? 1 : 0;
  const int nconvU = 6250, nconvI = full ? 6250 : 0;
  const void* Xi = full ? (const void*)Ei_b : (const void*)embed_item;

  prep_kernel<<<nconvU + nconvI + 209, 256, 0, stream>>>(
      embed_user, embed_item, Eu_b, Ei_b, bcnt,
      W0_uu, W0_ui, W0_iu, W1_uu, W1_iu, pW0_uu, pW0_ui, pW0_iu, pW1_uu, pW1_iu,
      nconvU, nconvI);

  scatter_kernel<<<3 * NSB, 256, 0, stream>>>(src_uu, dst_uu, src_iu, dst_iu,
                                              src_ui, dst_ui, bcnt, pairs);
  fine_sort_kernel<<<3 * NBUCK, 256, 0, stream>>>(pairs, bcnt,
                                                  off_uu, off_iu, off_ui,
                                                  ssrc_uu, ssrc_iu, ssrc_ui);

  const int nbi = NPAD / 16;  // 6252 single-wave blocks per class; user blocks first (LJF)
  fused_layer_kernel<<<2 * nbi, 64, 0, stream>>>(
      (const uint4*)Eu_b, Xi, full, off_ui, off_uu, off_iu,
      ssrc_ui, ssrc_uu, ssrc_iu,
      pW0_ui, pW0_uu, pW0_iu, b0_ui, b0_uu, b0_iu,
      pW1_iu, pW1_uu, b1_iu, b1_uu, P_iu, P_uu, nbi);

  out_kernel<<<NU / 16, 256, 0, stream>>>((const float4*)P_uu, (const float4*)P_iu,
                                          off_uu, ssrc_uu, off_iu, ssrc_iu,
                                          (float4*)out);
}

// Round 11
// 322.967 us; speedup vs baseline: 2.2701x; 1.0504x over previous
//
#include <hip/hip_runtime.h>
#include <hip/hip_bf16.h>

#define NU 100000
#define NI 100000
#define NEDGE 600000
#define DIN 128
#define DOUT 16
#define NPAD 100032   // 1563 * 64; also 6252 * 16
#define BSH 9         // coarse bucket shift
#define NBUCK 196     // ceil(100000 / 512)
#define NSB 256       // scatter blocks per etype
#define SCH 2344      // edges per scatter block (256*2344 >= 600000)
#define BSTRIDE 4096  // fixed pairs-slot per bucket (max bucket ~3250, 18-sigma margin)

typedef __attribute__((ext_vector_type(8))) short short8;
typedef __attribute__((ext_vector_type(4))) float f32x4;

// ---- workspace word offsets ----
#define W_EU   0ull          // 6,400,000 w bf16 user table (live until fused kernel done)
#define W_AUI  6400000ull    // packed pairs: 3 * 196 * 4096 = 2,408,448 u32 (sort scratch)
#define W_AUU  12802048ull   // bcnt (588 w) aliases head pre-fused; P_iu/P_uu after sort
#define W_AIU  19204096ull   // (unused now)
#define W_PW   25606144ull   // packed weights, 26,624 w
#define W_OFFU 25632768ull   // 100,016 w each
#define W_OFFI 25732784ull
#define W_OFFX 25832800ull
#define W_SUU  25932816ull   // 600,000 w each
#define W_SIU  26532816ull
#define W_SUI  27132816ull
#define W_EI   27732944ull   // 6,400,000 w (optional)
#define WS_FULL_BYTES (34132944ull * 4)

__device__ inline unsigned pack_bf16(float x, float y) {
  __hip_bfloat162 h = __float22bfloat162_rn(make_float2(x, y));
  unsigned u;
  __builtin_memcpy(&u, &h, 4);
  return u;
}

__device__ inline short bf16_bits(float x) {
  __hip_bfloat16 h = __float2bfloat16(x);
  short s;
  __builtin_memcpy(&s, &h, 2);
  return s;
}

__device__ inline void bf2_accw(unsigned u, float w, float& ax, float& ay) {
  unsigned lo = u << 16, hi = u & 0xffff0000u;
  float f0, f1;
  __builtin_memcpy(&f0, &lo, 4);
  __builtin_memcpy(&f1, &hi, 4);
  ax = fmaf(f0, w, ax);
  ay = fmaf(f1, w, ay);
}

// ---- merged prep+scatter: INDEPENDENT work units in one kernel ----
// blocks [0, 3*NSB): scatter (LDS hist -> atomic reserve -> packed u32 pair writes)
// blocks [3*NSB, 3*NSB+nconv): embed fp32->bf16 conversion
// blocks [3*NSB+nconv, +208): weight repack
// Scatter blocks dispatch FIRST (latency-bound) and overlap under the BW-bound conversion
// stream. bcnt is pre-zeroed via hipMemsetAsync (no in-kernel race).
__global__ __launch_bounds__(256) void prep_scatter_kernel(
    const float* __restrict__ Eu, const float* __restrict__ Ei,
    unsigned* __restrict__ Eu_b, unsigned* __restrict__ Ei_b,
    const int* __restrict__ s_uu, const int* __restrict__ d_uu,
    const int* __restrict__ s_iu, const int* __restrict__ d_iu,
    const int* __restrict__ s_ui, const int* __restrict__ d_ui,
    int* __restrict__ bcnt, unsigned* __restrict__ pairs,
    const float* __restrict__ W0_uu, const float* __restrict__ W0_ui,
    const float* __restrict__ W0_iu, const float* __restrict__ W1_uu,
    const float* __restrict__ W1_iu, short* __restrict__ pW0_uu, short* __restrict__ pW0_ui,
    short* __restrict__ pW0_iu, short* __restrict__ pW1_uu, short* __restrict__ pW1_iu,
    int nconvU, int nconvI) {
  __shared__ int h[NBUCK];
  __shared__ int cur[NBUCK];
  int b = blockIdx.x;
  int tid = threadIdx.x;

  if (b < 3 * NSB) {
    // ---- scatter path ----
    int t = b / NSB, k = b % NSB;
    const int* src = (t == 0) ? s_uu : (t == 1) ? s_iu : s_ui;
    const int* dst = (t == 0) ? d_uu : (t == 1) ? d_iu : d_ui;
    if (tid < NBUCK) h[tid] = 0;
    __syncthreads();
    int e0 = k * SCH, e1 = min(e0 + SCH, NEDGE);
    for (int e = e0 + tid; e < e1; e += 256) atomicAdd(&h[dst[e] >> BSH], 1);
    __syncthreads();
    if (tid < NBUCK) {
      int c = h[tid];
      int r = (c > 0) ? atomicAdd(&bcnt[t * NBUCK + tid], c) : 0;
      cur[tid] = t * (NBUCK * BSTRIDE) + tid * BSTRIDE + r;
    }
    __syncthreads();
    for (int e = e0 + tid; e < e1; e += 256) {
      int d = dst[e];
      int pos = atomicAdd(&cur[d >> BSH], 1);
      pairs[pos] = ((unsigned)(d & ((1 << BSH) - 1)) << 17) | (unsigned)src[e];
    }
    return;
  }
  b -= 3 * NSB;
  if (b < nconvU + nconvI) {
    // ---- embed conversion path ----
    const float* src;
    unsigned* dst;
    int t;
    if (b < nconvU) { src = Eu; dst = Eu_b; t = b * 256 + tid; }
    else { src = Ei; dst = Ei_b; t = (b - nconvU) * 256 + tid; }
    const float4* s4 = (const float4*)src;
    float4 x = s4[(size_t)t * 2], y = s4[(size_t)t * 2 + 1];
    uint4 o;
    o.x = pack_bf16(x.x, x.y);
    o.y = pack_bf16(x.z, x.w);
    o.z = pack_bf16(y.x, y.y);
    o.w = pack_bf16(y.z, y.w);
    ((uint4*)dst)[t] = o;
    return;
  }
  b -= nconvU + nconvI;
  // ---- weight repack path ----
  int t = b * 256 + tid;
  const float* src;
  short* dst;
  int base;
  bool w1 = false;
  if (t < 16384) { src = W0_uu; dst = pW0_uu; base = t; }
  else if (t < 32768) { src = W0_ui; dst = pW0_ui; base = t - 16384; }
  else if (t < 49152) { src = W0_iu; dst = pW0_iu; base = t - 32768; }
  else if (t < 51200) { src = W1_uu; dst = pW1_uu; base = t - 49152; w1 = true; }
  else if (t < 53248) { src = W1_iu; dst = pW1_iu; base = t - 51200; w1 = true; }
  else return;
  int j = base & 7;
  int lane = (base >> 3) & 63;
  int frag = base >> 9;
  int quad = lane >> 4, l16 = lane & 15;
  float val;
  if (!w1) {
    int kc = frag >> 3, nt = frag & 7;
    val = src[(kc * 32 + quad * 8 + j) * 128 + nt * 16 + l16];
  } else {
    int kc = frag;
    val = src[(kc * 32 + quad * 8 + j) * 16 + l16];
  }
  dst[base] = bf16_bits(val);
}

// -------- fine sort: redundant bucket-prefix + LDS hist/scan -> off[] + ssrc scatter --------
__global__ __launch_bounds__(256) void fine_sort_kernel(
    const unsigned* __restrict__ pairs, const int* __restrict__ bcnt,
    int* __restrict__ off_uu, int* __restrict__ off_iu, int* __restrict__ off_ui,
    int* __restrict__ ssrc_uu, int* __restrict__ ssrc_iu, int* __restrict__ ssrc_ui) {
  __shared__ int h[1 << BSH];
  __shared__ int wls[4];
  __shared__ int pfx[256];  // exclusive prefix of bucket counts (per etype)
  int t = blockIdx.x / NBUCK, b = blockIdx.x % NBUCK;
  int tid = threadIdx.x, lane = tid & 63, wv = tid >> 6;
  int* off = (t == 0) ? off_uu : (t == 1) ? off_iu : off_ui;
  int* ss = (t == 0) ? ssrc_uu : (t == 1) ? ssrc_iu : ssrc_ui;
  // ---- redundant per-block exclusive prefix over this etype's 196 bucket counts ----
  {
    int v = (tid < NBUCK) ? bcnt[t * NBUCK + tid] : 0;
    int x = v;
#pragma unroll
    for (int d = 1; d < 64; d <<= 1) {
      int y = __shfl_up(x, d, 64);
      if (lane >= d) x += y;
    }
    if (lane == 63) wls[wv] = x;
    __syncthreads();
    if (tid == 0) {
      int r = 0;
#pragma unroll
      for (int i = 0; i < 4; i++) { int tt = wls[i]; wls[i] = r; r += tt; }
    }
    __syncthreads();
    pfx[tid] = x - v + wls[wv];
    __syncthreads();
  }
  int base = b << BSH;
  int base_off = pfx[b];                  // this bucket's edge base in dense order
  int cnt = bcnt[t * NBUCK + b];
  const unsigned* pr = pairs + (size_t)t * (NBUCK * BSTRIDE) + (size_t)b * BSTRIDE;
  h[tid] = 0;
  h[tid + 256] = 0;
  __syncthreads();
  for (int e = tid; e < cnt; e += 256) atomicAdd(&h[pr[e] >> 17], 1);
  __syncthreads();
  int h0 = h[2 * tid], h1 = h[2 * tid + 1];
  int s = h0 + h1, x = s;
#pragma unroll
  for (int d = 1; d < 64; d <<= 1) {
    int y = __shfl_up(x, d, 64);
    if (lane >= d) x += y;
  }
  if (lane == 63) wls[wv] = x;
  __syncthreads();
  if (tid == 0) {
    int r = 0;
#pragma unroll
    for (int i = 0; i < 4; i++) { int tt = wls[i]; wls[i] = r; r += tt; }
  }
  __syncthreads();
  int excl = base_off + x - s + wls[wv];
  h[2 * tid] = excl;
  h[2 * tid + 1] = excl + h0;
  __syncthreads();
  int nn = min(1 << BSH, NU - base);
  for (int i = tid; i < nn; i += 256) off[base + i] = h[i];
  if (b == NBUCK - 1 && tid == 0) off[NU] = base_off + cnt;  // = NEDGE
  __syncthreads();
  for (int e = tid; e < cnt; e += 256) {
    unsigned p = pr[e];
    int pos = atomicAdd(&h[p >> 17], 1);
    ss[pos] = (int)(p & 0x1FFFFu);
  }
}

// ---------------- fused: gather+mean into LDS -> MFMA L0(+relu) -> MFMA L1 -> P ----------------
// ONE WAVE PER BLOCK (64 threads), 16 dst rows per block. R8/R10's measured-best body (fp32 h
// stride 20, VGPR 64, 106us): dual-row gather ILP, LJF ordering, kc=0 weight prefetch.
__global__ __launch_bounds__(64, 4) void fused_layer_kernel(
    const uint4* __restrict__ Xu4, const void* __restrict__ Xi, int xi_bf16,
    const int* __restrict__ off_ui, const int* __restrict__ off_uu, const int* __restrict__ off_iu,
    const int* __restrict__ s_ui, const int* __restrict__ s_uu, const int* __restrict__ s_iu,
    const short* __restrict__ pW0_ui, const short* __restrict__ pW0_uu,
    const short* __restrict__ pW0_iu, const float* __restrict__ b0_ui,
    const float* __restrict__ b0_uu, const float* __restrict__ b0_iu,
    const short* __restrict__ pW1_iu, const short* __restrict__ pW1_uu,
    const float* __restrict__ b1_iu, const float* __restrict__ b1_uu,
    float* __restrict__ P_iu, float* __restrict__ P_uu, int nbi) {
  __shared__ __align__(16) float hs[2560];

  const int lane = threadIdx.x;  // one wave
  const bool user = (int)blockIdx.x < nbi;   // LJF: user (long) blocks first
  const int blk = user ? (int)blockIdx.x : (int)blockIdx.x - nbi;
  const int rb = blk * 16;  // global row base of this wave's 16 rows

  float* hw = &hs[0];
  uint4* A0 = (uint4*)hw;        // 16 rows x 16 chunks(16B) = 4KB
  uint4* A1 = A0 + 256;          // next 4KB

  // ---- gather phase: 4 groups x 16 feature-lanes; group g does rows g*4..g*4+3,
  //      two rows in flight at a time (16 outstanding dwordx4 gathers) ----
  {
    const int g = lane >> 4, l16 = lane & 15;
    const int npass = user ? 2 : 1;
#pragma unroll 1
    for (int pass = 0; pass < npass; pass++) {
      const int* off = pass ? off_iu : (user ? off_uu : off_ui);
      const int* ss = pass ? s_iu : (user ? s_uu : s_ui);
      uint4* A = pass ? A1 : A0;
      const bool bf = pass ? (xi_bf16 != 0) : true;
      const uint4* X = pass ? (const uint4*)Xi : Xu4;
      const float4* Xf = (const float4*)Xi;
      if (bf) {
#pragma unroll 1
        for (int ip = 0; ip < 2; ip++) {
          int rA = g * 4 + ip * 2, rB = rA + 1;
          int nodeA = rb + rA, nodeB = rb + rB;
          float acA[8], acB[8];
#pragma unroll
          for (int j = 0; j < 8; j++) { acA[j] = 0.f; acB[j] = 0.f; }
          int s0A = 0, s1A = 0, s0B = 0, s1B = 0;
          if (nodeA < NU) { s0A = off[nodeA]; s1A = off[nodeA + 1]; }
          if (nodeB < NU) { s0B = off[nodeB]; s1B = off[nodeB + 1]; }
          int degA = s1A - s0A, degB = s1B - s0B;
#pragma unroll 1
          for (int eA = s0A, eB = s0B; eA < s1A || eB < s1B; eA += 8, eB += 8) {
            int idxA[8], idxB[8];
            float wtA[8], wtB[8];
#pragma unroll
            for (int j = 0; j < 8; j++) {
              int ea = eA + j, eb = eB + j;
              wtA[j] = (ea < s1A) ? 1.f : 0.f;
              wtB[j] = (eb < s1B) ? 1.f : 0.f;
              idxA[j] = ss[max(min(ea, s1A - 1), 0)];
              idxB[j] = ss[max(min(eb, s1B - 1), 0)];
            }
            uint4 vA[8], vB[8];
#pragma unroll
            for (int j = 0; j < 8; j++) vA[j] = X[(size_t)idxA[j] * 16 + l16];
#pragma unroll
            for (int j = 0; j < 8; j++) vB[j] = X[(size_t)idxB[j] * 16 + l16];
#pragma unroll
            for (int j = 0; j < 8; j++) {
              bf2_accw(vA[j].x, wtA[j], acA[0], acA[1]);
              bf2_accw(vA[j].y, wtA[j], acA[2], acA[3]);
              bf2_accw(vA[j].z, wtA[j], acA[4], acA[5]);
              bf2_accw(vA[j].w, wtA[j], acA[6], acA[7]);
            }
#pragma unroll
            for (int j = 0; j < 8; j++) {
              bf2_accw(vB[j].x, wtB[j], acB[0], acB[1]);
              bf2_accw(vB[j].y, wtB[j], acB[2], acB[3]);
              bf2_accw(vB[j].z, wtB[j], acB[4], acB[5]);
              bf2_accw(vB[j].w, wtB[j], acB[6], acB[7]);
            }
          }
          float invA = 1.0f / fmaxf((float)degA, 1.0f);
          float invB = 1.0f / fmaxf((float)degB, 1.0f);
          uint4 oA, oB;
          oA.x = pack_bf16(acA[0] * invA, acA[1] * invA);
          oA.y = pack_bf16(acA[2] * invA, acA[3] * invA);
          oA.z = pack_bf16(acA[4] * invA, acA[5] * invA);
          oA.w = pack_bf16(acA[6] * invA, acA[7] * invA);
          oB.x = pack_bf16(acB[0] * invB, acB[1] * invB);
          oB.y = pack_bf16(acB[2] * invB, acB[3] * invB);
          oB.z = pack_bf16(acB[4] * invB, acB[5] * invB);
          oB.w = pack_bf16(acB[6] * invB, acB[7] * invB);
          A[rA * 16 + (l16 ^ (rA & 7))] = oA;  // swizzled chunk store
          A[rB * 16 + (l16 ^ (rB & 7))] = oB;
        }
      } else {
        // fp32 fallback path (workspace-limited mode), per-row as before
#pragma unroll 1
        for (int it = 0; it < 4; it++) {
          int r = g * 4 + it;
          int node = rb + r;
          float ac[8];
#pragma unroll
          for (int j = 0; j < 8; j++) ac[j] = 0.f;
          int deg = 0;
          if (node < NU) {
            int s0 = off[node], s1 = off[node + 1];
            deg = s1 - s0;
            if (deg > 0) {
              for (int e = s0; e < s1; e += 4) {
                int idx[4];
                float wt[4];
#pragma unroll
                for (int j = 0; j < 4; j++) {
                  int ee = e + j;
                  bool v = ee < s1;
                  idx[j] = ss[v ? ee : s1 - 1];
                  wt[j] = v ? 1.f : 0.f;
                }
#pragma unroll
                for (int j = 0; j < 4; j++) {
                  float4 pa = Xf[(size_t)idx[j] * 32 + l16 * 2];
                  float4 qa = Xf[(size_t)idx[j] * 32 + l16 * 2 + 1];
                  ac[0] = fmaf(pa.x, wt[j], ac[0]); ac[1] = fmaf(pa.y, wt[j], ac[1]);
                  ac[2] = fmaf(pa.z, wt[j], ac[2]); ac[3] = fmaf(pa.w, wt[j], ac[3]);
                  ac[4] = fmaf(qa.x, wt[j], ac[4]); ac[5] = fmaf(qa.y, wt[j], ac[5]);
                  ac[6] = fmaf(qa.z, wt[j], ac[6]); ac[7] = fmaf(qa.w, wt[j], ac[7]);
                }
              }
            }
          }
          float inv = 1.0f / fmaxf((float)deg, 1.0f);
          uint4 o;
          o.x = pack_bf16(ac[0] * inv, ac[1] * inv);
          o.y = pack_bf16(ac[2] * inv, ac[3] * inv);
          o.z = pack_bf16(ac[4] * inv, ac[5] * inv);
          o.w = pack_bf16(ac[6] * inv, ac[7] * inv);
          A[r * 16 + (l16 ^ (r & 7))] = o;
        }
      }
    }
  }

  // ---- kc=0 weight prefetch (issued before barrier; hides L2 latency under gather drain) ----
  const short8* B0p = (const short8*)(user ? pW0_uu : pW0_ui);
  short8 b0pre[8];
#pragma unroll
  for (int nt = 0; nt < 8; nt++) b0pre[nt] = B0p[nt * 64 + lane];

  __syncthreads();  // single-wave barrier: orders LDS writes vs reads

  // ---- layer-0 MFMA (A from LDS) ----
  const int quad = lane >> 4, q16 = lane & 15;
  const int* off0 = user ? off_uu : off_ui;
  const float* b0a = user ? b0_uu : b0_ui;
  const short* W1p = user ? pW1_uu : pW1_iu;
  const float* b1v = user ? b1_uu : b1_iu;
  float* P = user ? P_uu : P_iu;

  float m0[4], m1[4];
#pragma unroll
  for (int r = 0; r < 4; r++) {
    int rr = rb + quad * 4 + r;
    m0[r] = 0.f;
    m1[r] = 0.f;
    if (rr < NU) {
      m0[r] = (off0[rr + 1] > off0[rr]) ? 1.f : 0.f;
      if (user) m1[r] = (off_iu[rr + 1] > off_iu[rr]) ? 1.f : 0.f;
    }
  }

  f32x4 acc[8];
#pragma unroll
  for (int nt = 0; nt < 8; nt++) {
    float ba = b0a[nt * 16 + q16];
    float bb = user ? b0_iu[nt * 16 + q16] : 0.f;
#pragma unroll
    for (int r = 0; r < 4; r++) acc[nt][r] = ba * m0[r] + bb * m1[r];
  }

  const short8* B1p = (const short8*)pW0_iu;
  union u4s8 { uint4 u; short8 s; };
#pragma unroll
  for (int kc = 0; kc < 4; kc++) {
    int c = kc * 4 + quad;
    u4s8 a0, a1;
    a0.u = A0[q16 * 16 + (c ^ (q16 & 7))];
    if (user) a1.u = A1[q16 * 16 + (c ^ (q16 & 7))];
#pragma unroll
    for (int nt = 0; nt < 8; nt++) {
      short8 b0 = (kc == 0) ? b0pre[nt] : B0p[(kc * 8 + nt) * 64 + lane];
      acc[nt] = __builtin_amdgcn_mfma_f32_16x16x32_bf16(a0.s, b0, acc[nt], 0, 0, 0);
      if (user) {
        short8 bb = B1p[(kc * 8 + nt) * 64 + lane];
        acc[nt] = __builtin_amdgcn_mfma_f32_16x16x32_bf16(a1.s, bb, acc[nt], 0, 0, 0);
      }
    }
  }
  __syncthreads();  // A tiles dead -> reuse region for h

  // ---- relu + h to LDS (col-major, stride 20) ----
#pragma unroll
  for (int nt = 0; nt < 8; nt++) {
    int col = nt * 16 + q16;
    float4 v;
    v.x = fmaxf(acc[nt][0], 0.f);
    v.y = fmaxf(acc[nt][1], 0.f);
    v.z = fmaxf(acc[nt][2], 0.f);
    v.w = fmaxf(acc[nt][3], 0.f);
    *(float4*)&hw[col * 20 + quad * 4] = v;
  }
  __syncthreads();

  // ---- layer-1 MFMA ----
  f32x4 acc2;
  {
    float bv = b1v[q16];
    acc2[0] = bv; acc2[1] = bv; acc2[2] = bv; acc2[3] = bv;
  }
  const short8* W1f = (const short8*)W1p;
#pragma unroll
  for (int kc = 0; kc < 4; kc++) {
    float f[8];
#pragma unroll
    for (int j = 0; j < 8; j++) f[j] = hw[(kc * 32 + quad * 8 + j) * 20 + q16];
    union { uint4 u; short8 s; } hf;
    hf.u.x = pack_bf16(f[0], f[1]);
    hf.u.y = pack_bf16(f[2], f[3]);
    hf.u.z = pack_bf16(f[4], f[5]);
    hf.u.w = pack_bf16(f[6], f[7]);
    short8 bw = W1f[kc * 64 + lane];
    acc2 = __builtin_amdgcn_mfma_f32_16x16x32_bf16(hf.s, bw, acc2, 0, 0, 0);
  }
#pragma unroll
  for (int r = 0; r < 4; r++) {
    int rr = rb + quad * 4 + r;
    if (rr < NU) P[(size_t)rr * DOUT + q16] = acc2[r];
  }
}

// ---------------- fused output: 4 nodes/wave x 4 edge-slots x float4, 4 edges in flight ----
__global__ __launch_bounds__(256) void out_kernel(const float4* __restrict__ P_uu,
                                                  const float4* __restrict__ P_iu,
                                                  const int* __restrict__ off_uu,
                                                  const int* __restrict__ s_uu,
                                                  const int* __restrict__ off_iu,
                                                  const int* __restrict__ s_iu,
                                                  float4* __restrict__ out) {
  int w = threadIdx.x >> 6, lane = threadIdx.x & 63;
  int q = lane & 3;            // float4 quad within 16-float row
  int sl = (lane >> 2) & 3;    // edge slot
  int nl = lane >> 4;          // node within wave
  int node = blockIdx.x * 16 + w * 4 + nl;  // NU == 6250*16 exactly
  float4 a = make_float4(0.f, 0.f, 0.f, 0.f);
  float4 b = a;
  int s0 = off_uu[node], s1 = off_uu[node + 1];
  for (int e = s0 + sl; e < s1; e += 16) {
    // 4 edges in flight per slot: clamp index, weight 0/1
    int idx[4];
    float wt[4];
#pragma unroll
    for (int j = 0; j < 4; j++) {
      int ee = e + j * 4;
      bool v = ee < s1;
      idx[j] = s_uu[v ? ee : s1 - 1];
      wt[j] = v ? 1.f : 0.f;
    }
    float4 vv[4];
#pragma unroll
    for (int j = 0; j < 4; j++) vv[j] = P_uu[(size_t)idx[j] * 4 + q];
#pragma unroll
    for (int j = 0; j < 4; j++) {
      a.x = fmaf(vv[j].x, wt[j], a.x); a.y = fmaf(vv[j].y, wt[j], a.y);
      a.z = fmaf(vv[j].z, wt[j], a.z); a.w = fmaf(vv[j].w, wt[j], a.w);
    }
  }
  int t0 = off_iu[node], t1 = off_iu[node + 1];
  for (int e = t0 + sl; e < t1; e += 16) {
    int idx[4];
    float wt[4];
#pragma unroll
    for (int j = 0; j < 4; j++) {
      int ee = e + j * 4;
      bool v = ee < t1;
      idx[j] = s_iu[v ? ee : t1 - 1];
      wt[j] = v ? 1.f : 0.f;
    }
    float4 vv[4];
#pragma unroll
    for (int j = 0; j < 4; j++) vv[j] = P_iu[(size_t)idx[j] * 4 + q];
#pragma unroll
    for (int j = 0; j < 4; j++) {
      b.x = fmaf(vv[j].x, wt[j], b.x); b.y = fmaf(vv[j].y, wt[j], b.y);
      b.z = fmaf(vv[j].z, wt[j], b.z); b.w = fmaf(vv[j].w, wt[j], b.w);
    }
  }
  float ia = 1.0f / fmaxf((float)(s1 - s0), 1.0f);
  float ib = 1.0f / fmaxf((float)(t1 - t0), 1.0f);
  float4 r;
  r.x = a.x * ia + b.x * ib;
  r.y = a.y * ia + b.y * ib;
  r.z = a.z * ia + b.z * ib;
  r.w = a.w * ia + b.w * ib;
  // reduce across the 4 edge slots (lane bits 2-3)
  r.x += __shfl_xor(r.x, 4, 64); r.y += __shfl_xor(r.y, 4, 64);
  r.z += __shfl_xor(r.z, 4, 64); r.w += __shfl_xor(r.w, 4, 64);
  r.x += __shfl_xor(r.x, 8, 64); r.y += __shfl_xor(r.y, 8, 64);
  r.z += __shfl_xor(r.z, 8, 64); r.w += __shfl_xor(r.w, 8, 64);
  if (sl == 0) out[(size_t)node * 4 + q] = r;
}

extern "C" void kernel_launch(void* const* d_in, const int* in_sizes, int n_in,
                              void* d_out, int out_size, void* d_ws, size_t ws_size,
                              hipStream_t stream) {
  (void)in_sizes; (void)n_in; (void)out_size;
  const float* embed_user = (const float*)d_in[0];
  const float* embed_item = (const float*)d_in[1];
  const int* src_uu = (const int*)d_in[2];
  const int* dst_uu = (const int*)d_in[3];
  const int* src_ui = (const int*)d_in[4];
  const int* dst_ui = (const int*)d_in[5];
  const int* src_iu = (const int*)d_in[6];
  const int* dst_iu = (const int*)d_in[7];
  const float* W0_uu = (const float*)d_in[8];
  const float* b0_uu = (const float*)d_in[9];
  const float* W0_ui = (const float*)d_in[10];
  const float* b0_ui = (const float*)d_in[11];
  const float* W0_iu = (const float*)d_in[12];
  const float* b0_iu = (const float*)d_in[13];
  const float* W1_uu = (const float*)d_in[14];
  const float* b1_uu = (const float*)d_in[15];
  const float* W1_iu = (const float*)d_in[18];
  const float* b1_iu = (const float*)d_in[19];
  float* out = (float*)d_out;

  char* ws = (char*)d_ws;
  unsigned* Eu_b = (unsigned*)(ws + W_EU * 4);
  short* pW0_uu = (short*)(ws + W_PW * 4);
  short* pW0_ui = pW0_uu + 16384;
  short* pW0_iu = pW0_uu + 32768;
  short* pW1_uu = pW0_uu + 49152;
  short* pW1_iu = pW0_uu + 51200;
  int* off_uu = (int*)(ws + W_OFFU * 4);
  int* off_iu = (int*)(ws + W_OFFI * 4);
  int* off_ui = (int*)(ws + W_OFFX * 4);
  int* ssrc_uu = (int*)(ws + W_SUU * 4);
  int* ssrc_iu = (int*)(ws + W_SIU * 4);
  int* ssrc_ui = (int*)(ws + W_SUI * 4);
  unsigned* Ei_b = (unsigned*)(ws + W_EI * 4);
  unsigned* pairs = (unsigned*)(ws + W_AUI * 4);  // 2,408,448 u32, dead after fine_sort
  int* bcnt = (int*)(ws + W_AUU * 4);             // 588 w, dead after fine_sort
  // P tables reuse the (dead after fine_sort) bcnt / A_uu region; Eu_b stays live through
  // the fused kernel (it is gathered there), so P may NOT alias Eu_b.
  float* P_iu = (float*)(ws + W_AUU * 4);
  float* P_uu = P_iu + 1600000;

  const int full = (ws_size >= WS_FULL_BYTES) ? 1 : 0;
  const int nconvU = 6250, nconvI = full ? 6250 : 0;
  const void* Xi = full ? (const void*)Ei_b : (const void*)embed_item;

  // zero bucket counters (stream-ordered, graph-capturable)
  hipMemsetAsync(bcnt, 0, 3 * NBUCK * sizeof(int), stream);

  // merged prep+scatter: scatter blocks first (latency-bound), conversion behind (BW-bound)
  prep_scatter_kernel<<<3 * NSB + nconvU + nconvI + 208, 256, 0, stream>>>(
      embed_user, embed_item, Eu_b, Ei_b,
      src_uu, dst_uu, src_iu, dst_iu, src_ui, dst_ui, bcnt, pairs,
      W0_uu, W0_ui, W0_iu, W1_uu, W1_iu, pW0_uu, pW0_ui, pW0_iu, pW1_uu, pW1_iu,
      nconvU, nconvI);

  fine_sort_kernel<<<3 * NBUCK, 256, 0, stream>>>(pairs, bcnt,
                                                  off_uu, off_iu, off_ui,
                                                  ssrc_uu, ssrc_iu, ssrc_ui);

  const int nbi = NPAD / 16;  // 6252 single-wave blocks per class; user blocks first (LJF)
  fused_layer_kernel<<<2 * nbi, 64, 0, stream>>>(
      (const uint4*)Eu_b, Xi, full, off_ui, off_uu, off_iu,
      ssrc_ui, ssrc_uu, ssrc_iu,
      pW0_ui, pW0_uu, pW0_iu, b0_ui, b0_uu, b0_iu,
      pW1_iu, pW1_uu, b1_iu, b1_uu, P_iu, P_uu, nbi);

  out_kernel<<<NU / 16, 256, 0, stream>>>((const float4*)P_uu, (const float4*)P_iu,
                                          off_uu, ssrc_uu, off_iu, ssrc_iu,
                                          (float4*)out);
}